// Round 1
// baseline (258.699 us; speedup 1.0000x reference)
//
#include <hip/hip_runtime.h>
#include <math.h>

#define HH 128
#define BB 2
#define NN 48
#define TT 24
#define MM 192
#define LL 20
#define NT (BB*NN*TT)   /* 2304 */
#define RAG 8
#define RSQRT_H 0.08838834764831845f  /* 1/sqrt(128) */

// ---------------- Kernel 1: map polyline encoder ----------------
// grid = B*M blocks, 128 threads (one per channel)
__global__ __launch_bounds__(128) void k_map_enc(
    const float* __restrict__ polylines, const float* __restrict__ poly_mask,
    const int* __restrict__ ptype, const int* __restrict__ tlst, const int* __restrict__ route,
    const float* __restrict__ mp_w0, const float* __restrict__ mp_b0,
    const float* __restrict__ mp_w1, const float* __restrict__ mp_b1,
    const float* __restrict__ type_emb, const float* __restrict__ tl_emb,
    const float* __restrict__ route_emb,
    const float* __restrict__ mo_w0, const float* __restrict__ mo_b0,
    const float* __restrict__ mo_w1, const float* __restrict__ mo_b1,
    float* __restrict__ map_node, float* __restrict__ map_center)
{
    int bm = blockIdx.x;
    int c  = threadIdx.x;
    __shared__ float pts[LL*2];
    __shared__ float h1[LL][HH];
    __shared__ float hb[HH];
    __shared__ float hb2[HH];

    const float* poly = polylines + (size_t)bm * LL * 2;
    if (c < LL*2) pts[c] = poly[c];
    __syncthreads();

    // layer 0: 2 -> 128, relu, for all 20 points
    {
        float w0x = mp_w0[c], w0y = mp_w0[HH + c], b0 = mp_b0[c];
        for (int p = 0; p < LL; ++p)
            h1[p][c] = fmaxf(fmaf(pts[2*p], w0x, fmaf(pts[2*p+1], w0y, b0)), 0.f);
    }
    // polyline center (mean over points)
    if (c < 2) {
        float s = 0.f;
        for (int p = 0; p < LL; ++p) s += pts[2*p + c];
        map_center[bm*2 + c] = s * (1.0f / LL);
    }
    __syncthreads();

    // layer 1: 128 -> 128, relu, maxpool over points.
    // One weight load reused for all 20 points.
    float acc[LL];
    {
        float b1 = mp_b1[c];
        #pragma unroll
        for (int p = 0; p < LL; ++p) acc[p] = b1;
        for (int k = 0; k < HH; ++k) {
            float wv = mp_w1[k*HH + c];
            #pragma unroll
            for (int p = 0; p < LL; ++p) acc[p] = fmaf(h1[p][k], wv, acc[p]);
        }
    }
    float hm = acc[0];
    #pragma unroll
    for (int p = 1; p < LL; ++p) hm = fmaxf(hm, acc[p]);
    hm = fmaxf(hm, 0.f);   // max of relu == relu of max

    int pt = ptype[bm]; pt = pt < 0 ? 0 : (pt > 3 ? 3 : pt);
    int tv = tlst[bm];  tv = tv < 0 ? 0 : (tv > 7 ? 7 : tv);
    int rv = route[bm]; rv = rv < 0 ? 0 : (rv > 1 ? 1 : rv);
    hm += type_emb[pt*HH + c] + tl_emb[tv*HH + c] + route_emb[rv*HH + c];

    hb[c] = hm;
    __syncthreads();
    float a2 = mo_b0[c];
    for (int k = 0; k < HH; ++k) a2 = fmaf(hb[k], mo_w0[k*HH + c], a2);
    hb2[c] = fmaxf(a2, 0.f);
    __syncthreads();
    float a3 = mo_b1[c];
    for (int k = 0; k < HH; ++k) a3 = fmaf(hb2[k], mo_w1[k*HH + c], a3);

    float mk = (poly_mask[bm] > 0.5f) ? 1.f : 0.f;
    map_node[(size_t)bm*HH + c] = a3 * mk;
}

// ---------------- Kernel 2: agent encoder ----------------
// grid = NT/RAG blocks, 128 threads; RAG rows per block
__global__ __launch_bounds__(128) void k_agent_enc(
    const float* __restrict__ astate, const float* __restrict__ amask,
    const float* __restrict__ ae_w0, const float* __restrict__ ae_b0,
    const float* __restrict__ ae_w1, const float* __restrict__ ae_b1,
    const float* __restrict__ ae_w2, const float* __restrict__ ae_b2,
    float* __restrict__ a_emb)
{
    int r0 = blockIdx.x * RAG;
    int c  = threadIdx.x;
    __shared__ float xin[RAG][5];
    __shared__ float h1[RAG][HH];
    __shared__ float h2[RAG][HH];

    if (c < RAG*5) xin[c/5][c%5] = astate[(size_t)r0*5 + c];
    __syncthreads();

    {
        float b = ae_b0[c];
        float w[5];
        #pragma unroll
        for (int i = 0; i < 5; ++i) w[i] = ae_w0[i*HH + c];
        #pragma unroll
        for (int r = 0; r < RAG; ++r) {
            float v = b;
            #pragma unroll
            for (int i = 0; i < 5; ++i) v = fmaf(xin[r][i], w[i], v);
            h1[r][c] = fmaxf(v, 0.f);
        }
    }
    __syncthreads();
    {
        float accv[RAG];
        float b = ae_b1[c];
        #pragma unroll
        for (int r = 0; r < RAG; ++r) accv[r] = b;
        for (int k = 0; k < HH; ++k) {
            float wv = ae_w1[k*HH + c];
            #pragma unroll
            for (int r = 0; r < RAG; ++r) accv[r] = fmaf(h1[r][k], wv, accv[r]);
        }
        #pragma unroll
        for (int r = 0; r < RAG; ++r) h2[r][c] = fmaxf(accv[r], 0.f);
    }
    __syncthreads();
    {
        float accv[RAG];
        float b = ae_b2[c];
        #pragma unroll
        for (int r = 0; r < RAG; ++r) accv[r] = b;
        for (int k = 0; k < HH; ++k) {
            float wv = ae_w2[k*HH + c];
            #pragma unroll
            for (int r = 0; r < RAG; ++r) accv[r] = fmaf(h2[r][k], wv, accv[r]);
        }
        #pragma unroll
        for (int r = 0; r < RAG; ++r)
            a_emb[(size_t)(r0 + r)*HH + c] = accv[r] * amask[r0 + r];
    }
}

// ---------------- Kernel 3: map cross-attention ----------------
// grid = NT blocks, 192 threads (one per map node in phase A)
__global__ __launch_bounds__(192) void k_map_attn(
    const float* __restrict__ astate,
    const float* __restrict__ a_emb, const float* __restrict__ map_node,
    const float* __restrict__ map_center, const float* __restrict__ poly_mask,
    const float* __restrict__ mr_w0, const float* __restrict__ mr_b0,
    const float* __restrict__ mr_w1, const float* __restrict__ mr_b1,
    float* __restrict__ map_ctx)
{
    int bnt = blockIdx.x;
    int b   = bnt / (NN*TT);
    int tid = threadIdx.x;
    __shared__ float aq[HH];
    __shared__ float lg[MM];
    __shared__ float pxy[2];
    __shared__ float smax, ssum;

    if (tid < HH) aq[tid] = a_emb[(size_t)bnt*HH + tid];
    if (tid < 2)  pxy[tid] = astate[(size_t)bnt*5 + tid];
    __syncthreads();

    // phase A: logits (one thread per map node)
    {
        int m = tid;
        float rx = map_center[(b*MM + m)*2]     - pxy[0];
        float ry = map_center[(b*MM + m)*2 + 1] - pxy[1];
        float rd = sqrtf(rx*rx + ry*ry);
        float s  = mr_b1[0];
        float dot = 0.f;
        const float* mn = map_node + (size_t)(b*MM + m)*HH;
        for (int k = 0; k < HH; ++k) {
            float h = fmaf(rx, mr_w0[k],
                      fmaf(ry, mr_w0[HH + k],
                      fmaf(rd, mr_w0[2*HH + k], mr_b0[k])));
            s   = fmaf(fmaxf(h, 0.f), mr_w1[k], s);
            dot = fmaf(aq[k], mn[k], dot);
        }
        float logit = fmaf(dot, RSQRT_H, s);
        lg[m] = (poly_mask[b*MM + m] > 0.5f) ? logit : -1e9f;
    }
    __syncthreads();

    // softmax over 192 logits
    if (tid < 64) {
        float v = fmaxf(fmaxf(lg[tid], lg[tid + 64]), lg[tid + 128]);
        #pragma unroll
        for (int o = 32; o > 0; o >>= 1) v = fmaxf(v, __shfl_xor(v, o));
        if (tid == 0) smax = v;
    }
    __syncthreads();
    lg[tid] = expf(lg[tid] - smax);
    __syncthreads();
    if (tid < 64) {
        float v = lg[tid] + lg[tid + 64] + lg[tid + 128];
        #pragma unroll
        for (int o = 32; o > 0; o >>= 1) v += __shfl_xor(v, o);
        if (tid == 0) ssum = v;
    }
    __syncthreads();

    // phase C: context (one thread per channel, coalesced over d)
    if (tid < HH) {
        float acc = 0.f;
        const float* mnb = map_node + (size_t)b*MM*HH + tid;
        for (int m = 0; m < MM; ++m) acc = fmaf(lg[m], mnb[(size_t)m*HH], acc);
        map_ctx[(size_t)bnt*HH + tid] = acc / ssum;
    }
}

// ---------------- Kernel 4: neighbor attention ----------------
// grid = NT blocks, 128 threads
__global__ __launch_bounds__(128) void k_nbr_attn(
    const float* __restrict__ astate, const float* __restrict__ amask,
    const float* __restrict__ a_emb,
    const float* __restrict__ nr_w0, const float* __restrict__ nr_b0,
    const float* __restrict__ nr_w1, const float* __restrict__ nr_b1,
    float* __restrict__ nbr_ctx)
{
    int bnt = blockIdx.x;
    int b   = bnt / (NN*TT);
    int n   = (bnt / TT) % NN;
    int t   = bnt % TT;
    int tid = threadIdx.x;
    __shared__ float aq[HH];
    __shared__ float lg[NN];
    __shared__ float self5[5];
    __shared__ float vmask_i;
    __shared__ float smax, ssum;

    aq[tid] = a_emb[(size_t)bnt*HH + tid];
    if (tid < 5)  self5[tid] = astate[(size_t)bnt*5 + tid];
    if (tid == 0) vmask_i = amask[bnt];
    __syncthreads();

    if (tid < NN) {
        int j = tid;
        int rowj = (b*NN + j)*TT + t;
        float dx  = self5[0] - astate[(size_t)rowj*5];
        float dy  = self5[1] - astate[(size_t)rowj*5 + 1];
        float dvx = self5[3] - astate[(size_t)rowj*5 + 3];
        float dvy = self5[4] - astate[(size_t)rowj*5 + 4];
        float dist = sqrtf(dx*dx + dy*dy);
        float s = nr_b1[0];
        float dot = 0.f;
        const float* aj = a_emb + (size_t)rowj*HH;
        for (int k = 0; k < HH; ++k) {
            float h = fmaf(dx,  nr_w0[k],
                      fmaf(dy,  nr_w0[HH + k],
                      fmaf(dvx, nr_w0[2*HH + k],
                      fmaf(dvy, nr_w0[3*HH + k],
                      fmaf(dist, nr_w0[4*HH + k], nr_b0[k])))));
            s   = fmaf(fmaxf(h, 0.f), nr_w1[k], s);
            dot = fmaf(aq[k], aj[k], dot);
        }
        bool ok = (vmask_i > 0.5f) && (amask[rowj] > 0.5f) &&
                  (dist <= 30.0f) && (j != n);
        lg[j] = ok ? fmaf(dot, RSQRT_H, s) : -1e9f;
    }
    __syncthreads();

    if (tid < 64) {
        float v = (tid < NN) ? lg[tid] : -3.4e38f;
        #pragma unroll
        for (int o = 32; o > 0; o >>= 1) v = fmaxf(v, __shfl_xor(v, o));
        if (tid == 0) smax = v;
    }
    __syncthreads();
    if (tid < NN) lg[tid] = expf(lg[tid] - smax);
    __syncthreads();
    if (tid < 64) {
        float v = (tid < NN) ? lg[tid] : 0.f;
        #pragma unroll
        for (int o = 32; o > 0; o >>= 1) v += __shfl_xor(v, o);
        if (tid == 0) ssum = v;
    }
    __syncthreads();

    {
        float acc = 0.f;
        for (int j = 0; j < NN; ++j)
            acc = fmaf(lg[j], a_emb[(size_t)((b*NN + j)*TT + t)*HH + tid], acc);
        nbr_ctx[(size_t)bnt*HH + tid] = acc / ssum;
    }
}

// ---------------- Kernel 5: output MLP ----------------
// grid = NT/RAG blocks, 128 threads
__global__ __launch_bounds__(128) void k_tau(
    const float* __restrict__ amask,
    const float* __restrict__ a_emb, const float* __restrict__ map_ctx,
    const float* __restrict__ nbr_ctx,
    const float* __restrict__ to_w0, const float* __restrict__ to_b0,
    const float* __restrict__ to_w1, const float* __restrict__ to_b1,
    float* __restrict__ tau)
{
    int r0 = blockIdx.x * RAG;
    int c  = threadIdx.x;
    __shared__ float xin[RAG][3*HH];
    __shared__ float h1[RAG][HH];

    for (int r = 0; r < RAG; ++r) {
        int row = r0 + r;
        xin[r][c]        = a_emb[(size_t)row*HH + c];
        xin[r][HH + c]   = map_ctx[(size_t)row*HH + c];
        xin[r][2*HH + c] = nbr_ctx[(size_t)row*HH + c];
    }
    __syncthreads();
    {
        float accv[RAG];
        float bb = to_b0[c];
        #pragma unroll
        for (int r = 0; r < RAG; ++r) accv[r] = bb;
        for (int k = 0; k < 3*HH; ++k) {
            float wv = to_w0[k*HH + c];
            #pragma unroll
            for (int r = 0; r < RAG; ++r) accv[r] = fmaf(xin[r][k], wv, accv[r]);
        }
        #pragma unroll
        for (int r = 0; r < RAG; ++r) h1[r][c] = fmaxf(accv[r], 0.f);
    }
    __syncthreads();
    if (c < 64) {
        float accv[RAG];
        float bb = to_b1[c];
        #pragma unroll
        for (int r = 0; r < RAG; ++r) accv[r] = bb;
        for (int k = 0; k < HH; ++k) {
            float wv = to_w1[k*64 + c];
            #pragma unroll
            for (int r = 0; r < RAG; ++r) accv[r] = fmaf(h1[r][k], wv, accv[r]);
        }
        #pragma unroll
        for (int r = 0; r < RAG; ++r)
            tau[(size_t)(r0 + r)*64 + c] = accv[r] * amask[r0 + r];
    }
}

extern "C" void kernel_launch(void* const* d_in, const int* in_sizes, int n_in,
                              void* d_out, int out_size, void* d_ws, size_t ws_size,
                              hipStream_t stream)
{
    const float* astate    = (const float*)d_in[0];
    const float* amask     = (const float*)d_in[1];
    const float* polylines = (const float*)d_in[2];
    const float* poly_mask = (const float*)d_in[3];
    const int*   ptype     = (const int*)d_in[4];
    const int*   tlst      = (const int*)d_in[5];
    const int*   route     = (const int*)d_in[6];
    const float* ae_w0 = (const float*)d_in[7];
    const float* ae_b0 = (const float*)d_in[8];
    const float* ae_w1 = (const float*)d_in[9];
    const float* ae_b1 = (const float*)d_in[10];
    const float* ae_w2 = (const float*)d_in[11];
    const float* ae_b2 = (const float*)d_in[12];
    const float* mp_w0 = (const float*)d_in[13];
    const float* mp_b0 = (const float*)d_in[14];
    const float* mp_w1 = (const float*)d_in[15];
    const float* mp_b1 = (const float*)d_in[16];
    const float* type_emb  = (const float*)d_in[17];
    const float* tl_emb    = (const float*)d_in[18];
    const float* route_emb = (const float*)d_in[19];
    const float* mo_w0 = (const float*)d_in[20];
    const float* mo_b0 = (const float*)d_in[21];
    const float* mo_w1 = (const float*)d_in[22];
    const float* mo_b1 = (const float*)d_in[23];
    const float* mr_w0 = (const float*)d_in[24];
    const float* mr_b0 = (const float*)d_in[25];
    const float* mr_w1 = (const float*)d_in[26];
    const float* mr_b1 = (const float*)d_in[27];
    const float* nr_w0 = (const float*)d_in[28];
    const float* nr_b0 = (const float*)d_in[29];
    const float* nr_w1 = (const float*)d_in[30];
    const float* nr_b1 = (const float*)d_in[31];
    const float* to_w0 = (const float*)d_in[32];
    const float* to_b0 = (const float*)d_in[33];
    const float* to_w1 = (const float*)d_in[34];
    const float* to_b1 = (const float*)d_in[35];

    float* tau     = (float*)d_out;                     // NT*64
    float* map_ctx = (float*)d_out + (size_t)NT*64;     // NT*128
    float* nbr_ctx = map_ctx + (size_t)NT*HH;           // NT*128

    float* ws         = (float*)d_ws;
    float* a_emb      = ws;                             // NT*HH
    float* map_node   = a_emb + (size_t)NT*HH;          // B*M*HH
    float* map_center = map_node + (size_t)BB*MM*HH;    // B*M*2

    k_map_enc<<<BB*MM, 128, 0, stream>>>(polylines, poly_mask, ptype, tlst, route,
        mp_w0, mp_b0, mp_w1, mp_b1, type_emb, tl_emb, route_emb,
        mo_w0, mo_b0, mo_w1, mo_b1, map_node, map_center);

    k_agent_enc<<<NT/RAG, 128, 0, stream>>>(astate, amask,
        ae_w0, ae_b0, ae_w1, ae_b1, ae_w2, ae_b2, a_emb);

    k_map_attn<<<NT, 192, 0, stream>>>(astate, a_emb, map_node, map_center,
        poly_mask, mr_w0, mr_b0, mr_w1, mr_b1, map_ctx);

    k_nbr_attn<<<NT, 128, 0, stream>>>(astate, amask, a_emb,
        nr_w0, nr_b0, nr_w1, nr_b1, nbr_ctx);

    k_tau<<<NT/RAG, 128, 0, stream>>>(amask, a_emb, map_ctx, nbr_ctx,
        to_w0, to_b0, to_w1, to_b1, tau);
}

// Round 2
// 237.950 us; speedup vs baseline: 1.0872x; 1.0872x over previous
//
#include <hip/hip_runtime.h>
#include <math.h>

#define HH 128
#define BB 2
#define NN 48
#define TT 24
#define MM 192
#define LL 20
#define NT (BB*NN*TT)   /* 2304 */
#define RSQRT_H 0.08838834764831845f  /* 1/sqrt(128) */

// ---------------- Kernel 1: map polyline encoder ----------------
// grid = B*M blocks, 512 threads: (pp = tid/128 in 0..3, c = tid%128)
__global__ __launch_bounds__(512) void k_map_enc(
    const float* __restrict__ polylines, const float* __restrict__ poly_mask,
    const int* __restrict__ ptype, const int* __restrict__ tlst, const int* __restrict__ route,
    const float* __restrict__ mp_w0, const float* __restrict__ mp_b0,
    const float* __restrict__ mp_w1, const float* __restrict__ mp_b1,
    const float* __restrict__ type_emb, const float* __restrict__ tl_emb,
    const float* __restrict__ route_emb,
    const float* __restrict__ mo_w0, const float* __restrict__ mo_b0,
    const float* __restrict__ mo_w1, const float* __restrict__ mo_b1,
    float* __restrict__ map_node, float* __restrict__ map_nodeT,
    float* __restrict__ map_center)
{
    int bm  = blockIdx.x;
    int tid = threadIdx.x;
    int pp  = tid >> 7;     // 0..3
    int c   = tid & 127;

    __shared__ float pts[LL*2];
    __shared__ float h1[LL][HH];
    __shared__ float mx[4][HH];
    __shared__ float hb[HH];
    __shared__ float pr[4][HH];
    __shared__ float hb2[HH];

    if (tid < LL*2) pts[tid] = polylines[(size_t)bm*LL*2 + tid];
    __syncthreads();

    // layer0: 2 -> 128 relu; each (pp,c) covers points p = pp + 4*i
    {
        float w0x = mp_w0[c], w0y = mp_w0[HH + c], b0 = mp_b0[c];
        #pragma unroll
        for (int i = 0; i < 5; ++i) {
            int p = pp + 4*i;
            h1[p][c] = fmaxf(fmaf(pts[2*p], w0x, fmaf(pts[2*p+1], w0y, b0)), 0.f);
        }
    }
    if (tid < 2) {
        float s = 0.f;
        for (int p = 0; p < LL; ++p) s += pts[2*p + tid];
        map_center[bm*2 + tid] = s * (1.0f / LL);
    }
    __syncthreads();

    // layer1: 128 -> 128 + maxpool over the 5 points this (pp,c) owns
    {
        float acc[5];
        float b1 = mp_b1[c];
        #pragma unroll
        for (int i = 0; i < 5; ++i) acc[i] = b1;
        for (int k = 0; k < HH; ++k) {
            float wv = mp_w1[k*HH + c];
            #pragma unroll
            for (int i = 0; i < 5; ++i) acc[i] = fmaf(h1[pp + 4*i][k], wv, acc[i]);
        }
        float m5 = acc[0];
        #pragma unroll
        for (int i = 1; i < 5; ++i) m5 = fmaxf(m5, acc[i]);
        mx[pp][c] = m5;
    }
    __syncthreads();

    if (tid < HH) {
        float hm = fmaxf(fmaxf(mx[0][c], mx[1][c]), fmaxf(mx[2][c], mx[3][c]));
        hm = fmaxf(hm, 0.f);
        int pt = ptype[bm]; pt = pt < 0 ? 0 : (pt > 3 ? 3 : pt);
        int tv = tlst[bm];  tv = tv < 0 ? 0 : (tv > 7 ? 7 : tv);
        int rv = route[bm]; rv = rv < 0 ? 0 : (rv > 1 ? 1 : rv);
        hm += type_emb[pt*HH + c] + tl_emb[tv*HH + c] + route_emb[rv*HH + c];
        hb[c] = hm;
    }
    __syncthreads();

    // mo layer0: 4-way k-split
    {
        float s = 0.f;
        int k0 = pp*32;
        for (int k = k0; k < k0 + 32; ++k) s = fmaf(hb[k], mo_w0[k*HH + c], s);
        pr[pp][c] = s;
    }
    __syncthreads();
    if (tid < HH) hb2[c] = fmaxf(pr[0][c] + pr[1][c] + pr[2][c] + pr[3][c] + mo_b0[c], 0.f);
    __syncthreads();
    {
        float s = 0.f;
        int k0 = pp*32;
        for (int k = k0; k < k0 + 32; ++k) s = fmaf(hb2[k], mo_w1[k*HH + c], s);
        pr[pp][c] = s;
    }
    __syncthreads();
    if (tid < HH) {
        float a3 = pr[0][c] + pr[1][c] + pr[2][c] + pr[3][c] + mo_b1[0*HH + c];
        float mk = (poly_mask[bm] > 0.5f) ? 1.f : 0.f;
        float v = a3 * mk;
        map_node[(size_t)bm*HH + c] = v;
        int b = bm / MM, m = bm % MM;
        map_nodeT[((size_t)b*HH + c)*MM + m] = v;
    }
}

// ---------------- Kernel 2: agent encoder ----------------
// grid = NT/4 blocks, 256 threads: (h = tid/128 in 0..1, c = tid%128), 4 rows/block
__global__ __launch_bounds__(256) void k_agent_enc(
    const float* __restrict__ astate, const float* __restrict__ amask,
    const float* __restrict__ ae_w0, const float* __restrict__ ae_b0,
    const float* __restrict__ ae_w1, const float* __restrict__ ae_b1,
    const float* __restrict__ ae_w2, const float* __restrict__ ae_b2,
    float* __restrict__ a_emb, float* __restrict__ a_embT)
{
    int r0  = blockIdx.x * 4;
    int tid = threadIdx.x;
    int h   = tid >> 7;
    int c   = tid & 127;

    __shared__ float xin[4][5];
    __shared__ float h1[4][HH];
    __shared__ float h2[4][HH];
    __shared__ float p1[2][4][HH];

    if (tid < 20) xin[tid/5][tid%5] = astate[(size_t)r0*5 + tid];
    __syncthreads();

    if (h == 0) {
        float b = ae_b0[c];
        float w[5];
        #pragma unroll
        for (int i = 0; i < 5; ++i) w[i] = ae_w0[i*HH + c];
        #pragma unroll
        for (int r = 0; r < 4; ++r) {
            float v = b;
            #pragma unroll
            for (int i = 0; i < 5; ++i) v = fmaf(xin[r][i], w[i], v);
            h1[r][c] = fmaxf(v, 0.f);
        }
    }
    __syncthreads();

    // layer1: 2-way k-split
    {
        float acc[4] = {0.f, 0.f, 0.f, 0.f};
        int k0 = h*64;
        for (int k = k0; k < k0 + 64; ++k) {
            float wv = ae_w1[k*HH + c];
            #pragma unroll
            for (int r = 0; r < 4; ++r) acc[r] = fmaf(h1[r][k], wv, acc[r]);
        }
        #pragma unroll
        for (int r = 0; r < 4; ++r) p1[h][r][c] = acc[r];
    }
    __syncthreads();
    {
        #pragma unroll
        for (int rr = 0; rr < 2; ++rr) {
            int r = h*2 + rr;
            h2[r][c] = fmaxf(p1[0][r][c] + p1[1][r][c] + ae_b1[c], 0.f);
        }
    }
    __syncthreads();

    // layer2: 2-way k-split
    {
        float acc[4] = {0.f, 0.f, 0.f, 0.f};
        int k0 = h*64;
        for (int k = k0; k < k0 + 64; ++k) {
            float wv = ae_w2[k*HH + c];
            #pragma unroll
            for (int r = 0; r < 4; ++r) acc[r] = fmaf(h2[r][k], wv, acc[r]);
        }
        #pragma unroll
        for (int r = 0; r < 4; ++r) p1[h][r][c] = acc[r];
    }
    __syncthreads();
    {
        #pragma unroll
        for (int rr = 0; rr < 2; ++rr) {
            int r = h*2 + rr;
            int row = r0 + r;
            float v = (p1[0][r][c] + p1[1][r][c] + ae_b2[c]) * amask[row];
            a_emb[(size_t)row*HH + c] = v;
            int bq  = row / (NN*TT);
            int rem = row % (NN*TT);
            int nq  = rem / TT;
            int tq  = rem % TT;
            a_embT[((size_t)(bq*TT + tq)*HH + c)*NN + nq] = v;
        }
    }
}

// ---------------- Kernel 3: map cross-attention ----------------
// grid = NT blocks, 384 threads
__global__ __launch_bounds__(384) void k_map_attn(
    const float* __restrict__ astate,
    const float* __restrict__ a_emb, const float* __restrict__ map_node,
    const float* __restrict__ map_nodeT,
    const float* __restrict__ map_center, const float* __restrict__ poly_mask,
    const float* __restrict__ mr_w0, const float* __restrict__ mr_b0,
    const float* __restrict__ mr_w1, const float* __restrict__ mr_b1,
    float* __restrict__ map_ctx)
{
    int bnt = blockIdx.x;
    int b   = bnt / (NN*TT);
    int tid = threadIdx.x;

    __shared__ float aq[HH];
    __shared__ float lg[MM];
    __shared__ float sA[2][MM], dA[2][MM];
    __shared__ float pc[3][HH];
    __shared__ float pxy[2];
    __shared__ float smax, ssum;

    if (tid < HH) aq[tid] = a_emb[(size_t)bnt*HH + tid];
    if (tid < 2)  pxy[tid] = astate[(size_t)bnt*5 + tid];
    __syncthreads();

    // phase A: logits, 2-way k-split, coalesced dot via map_nodeT
    {
        int half = tid / 192;
        int m    = tid - half*192;
        float rx = map_center[(b*MM + m)*2]     - pxy[0];
        float ry = map_center[(b*MM + m)*2 + 1] - pxy[1];
        float rd = sqrtf(rx*rx + ry*ry);
        const float* mnT = map_nodeT + (size_t)b*HH*MM;
        float s = 0.f, dot = 0.f;
        int k0 = half*64;
        for (int k = k0; k < k0 + 64; ++k) {
            float hrel = fmaf(rx, mr_w0[k],
                         fmaf(ry, mr_w0[HH + k],
                         fmaf(rd, mr_w0[2*HH + k], mr_b0[k])));
            s   = fmaf(fmaxf(hrel, 0.f), mr_w1[k], s);
            dot = fmaf(aq[k], mnT[(size_t)k*MM + m], dot);
        }
        sA[half][m] = s;
        dA[half][m] = dot;
    }
    __syncthreads();
    if (tid < MM) {
        float logit = fmaf(dA[0][tid] + dA[1][tid], RSQRT_H,
                           sA[0][tid] + sA[1][tid] + mr_b1[0]);
        lg[tid] = (poly_mask[b*MM + tid] > 0.5f) ? logit : -1e9f;
    }
    __syncthreads();

    if (tid < 64) {
        float v = fmaxf(fmaxf(lg[tid], lg[tid + 64]), lg[tid + 128]);
        #pragma unroll
        for (int o = 32; o > 0; o >>= 1) v = fmaxf(v, __shfl_xor(v, o));
        if (tid == 0) smax = v;
    }
    __syncthreads();
    if (tid < MM) lg[tid] = expf(lg[tid] - smax);
    __syncthreads();
    if (tid < 64) {
        float v = lg[tid] + lg[tid + 64] + lg[tid + 128];
        #pragma unroll
        for (int o = 32; o > 0; o >>= 1) v += __shfl_xor(v, o);
        if (tid == 0) ssum = v;
    }
    __syncthreads();

    // phase C: 3-way m-split, coalesced over c
    {
        int g = tid >> 7;   // 0..2
        int c = tid & 127;
        float acc = 0.f;
        const float* mnb = map_node + ((size_t)b*MM + g*64)*HH + c;
        for (int m = 0; m < 64; ++m) acc = fmaf(lg[g*64 + m], mnb[(size_t)m*HH], acc);
        pc[g][c] = acc;
    }
    __syncthreads();
    if (tid < HH) map_ctx[(size_t)bnt*HH + tid] = (pc[0][tid] + pc[1][tid] + pc[2][tid]) / ssum;
}

// ---------------- Kernel 4: neighbor attention ----------------
// grid = NT blocks, 256 threads
__global__ __launch_bounds__(256) void k_nbr_attn(
    const float* __restrict__ astate, const float* __restrict__ amask,
    const float* __restrict__ a_emb, const float* __restrict__ a_embT,
    const float* __restrict__ nr_w0, const float* __restrict__ nr_b0,
    const float* __restrict__ nr_w1, const float* __restrict__ nr_b1,
    float* __restrict__ nbr_ctx)
{
    int bnt = blockIdx.x;
    int b   = bnt / (NN*TT);
    int n   = (bnt / TT) % NN;
    int t   = bnt % TT;
    int tid = threadIdx.x;

    __shared__ float aq[HH];
    __shared__ float lg[64];
    __shared__ float sP[4][NN], dP[4][NN];
    __shared__ float dj[NN];
    __shared__ float pc[2][HH];
    __shared__ float self5[5];
    __shared__ float vmask_i;
    __shared__ float smax, ssum;

    if (tid < HH) aq[tid] = a_emb[(size_t)bnt*HH + tid];
    if (tid < 5)  self5[tid] = astate[(size_t)bnt*5 + tid];
    if (tid == 5) vmask_i = amask[bnt];
    __syncthreads();

    // phase A: 4-way k-split over j = tid%64 (j < 48 active)
    {
        int q = tid >> 6;   // 0..3
        int j = tid & 63;
        if (j < NN) {
            int rowj = (b*NN + j)*TT + t;
            float dx  = self5[0] - astate[(size_t)rowj*5];
            float dy  = self5[1] - astate[(size_t)rowj*5 + 1];
            float dvx = self5[3] - astate[(size_t)rowj*5 + 3];
            float dvy = self5[4] - astate[(size_t)rowj*5 + 4];
            float dist = sqrtf(dx*dx + dy*dy);
            if (q == 0) dj[j] = dist;
            const float* aT = a_embT + (size_t)(b*TT + t)*HH*NN;
            float s = 0.f, dot = 0.f;
            int k0 = q*32;
            for (int k = k0; k < k0 + 32; ++k) {
                float hrel = fmaf(dx,  nr_w0[k],
                             fmaf(dy,  nr_w0[HH + k],
                             fmaf(dvx, nr_w0[2*HH + k],
                             fmaf(dvy, nr_w0[3*HH + k],
                             fmaf(dist, nr_w0[4*HH + k], nr_b0[k])))));
                s   = fmaf(fmaxf(hrel, 0.f), nr_w1[k], s);
                dot = fmaf(aq[k], aT[(size_t)k*NN + j], dot);
            }
            sP[q][j] = s;
            dP[q][j] = dot;
        }
    }
    __syncthreads();
    if (tid < NN) {
        int j = tid;
        int rowj = (b*NN + j)*TT + t;
        float s   = sP[0][j] + sP[1][j] + sP[2][j] + sP[3][j] + nr_b1[0];
        float dot = dP[0][j] + dP[1][j] + dP[2][j] + dP[3][j];
        bool ok = (vmask_i > 0.5f) && (amask[rowj] > 0.5f) &&
                  (dj[j] <= 30.0f) && (j != n);
        lg[j] = ok ? fmaf(dot, RSQRT_H, s) : -1e9f;
    }
    __syncthreads();

    if (tid < 64) {
        float v = (tid < NN) ? lg[tid] : -3.4e38f;
        #pragma unroll
        for (int o = 32; o > 0; o >>= 1) v = fmaxf(v, __shfl_xor(v, o));
        if (tid == 0) smax = v;
    }
    __syncthreads();
    if (tid < NN) lg[tid] = expf(lg[tid] - smax);
    __syncthreads();
    if (tid < 64) {
        float v = (tid < NN) ? lg[tid] : 0.f;
        #pragma unroll
        for (int o = 32; o > 0; o >>= 1) v += __shfl_xor(v, o);
        if (tid == 0) ssum = v;
    }
    __syncthreads();

    // phase C: 2-way j-split, coalesced over c
    {
        int g = tid >> 7;   // 0..1
        int c = tid & 127;
        float acc = 0.f;
        int j0 = g*24;
        for (int j = j0; j < j0 + 24; ++j)
            acc = fmaf(lg[j], a_emb[((size_t)(b*NN + j)*TT + t)*HH + c], acc);
        pc[g][c] = acc;
    }
    __syncthreads();
    if (tid < HH) nbr_ctx[(size_t)bnt*HH + tid] = (pc[0][tid] + pc[1][tid]) / ssum;
}

// ---------------- Kernel 5: output MLP ----------------
// grid = NT/2 blocks, 256 threads: (h = tid/128, c = tid%128), 2 rows/block
__global__ __launch_bounds__(256) void k_tau(
    const float* __restrict__ amask,
    const float* __restrict__ a_emb, const float* __restrict__ map_ctx,
    const float* __restrict__ nbr_ctx,
    const float* __restrict__ to_w0, const float* __restrict__ to_b0,
    const float* __restrict__ to_w1, const float* __restrict__ to_b1,
    float* __restrict__ tau)
{
    int r0  = blockIdx.x * 2;
    int tid = threadIdx.x;
    int h   = tid >> 7;
    int c   = tid & 127;

    __shared__ float xin[2][3*HH];
    __shared__ float p1[2][2][HH];
    __shared__ float h1s[2][HH];
    __shared__ float p2[2][HH];

    for (int idx = tid; idx < 2*3*HH; idx += 256) {
        int r = idx / (3*HH);
        int k = idx % (3*HH);
        float v;
        if      (k < HH)   v = a_emb  [(size_t)(r0 + r)*HH + k];
        else if (k < 2*HH) v = map_ctx[(size_t)(r0 + r)*HH + (k - HH)];
        else               v = nbr_ctx[(size_t)(r0 + r)*HH + (k - 2*HH)];
        xin[r][k] = v;
    }
    __syncthreads();

    // layer0: 384 -> 128, 2-way k-split
    {
        float a0 = 0.f, a1 = 0.f;
        int k0 = h*192;
        for (int k = k0; k < k0 + 192; ++k) {
            float wv = to_w0[k*HH + c];
            a0 = fmaf(xin[0][k], wv, a0);
            a1 = fmaf(xin[1][k], wv, a1);
        }
        p1[h][0][c] = a0;
        p1[h][1][c] = a1;
    }
    __syncthreads();
    h1s[h][c] = fmaxf(p1[0][h][c] + p1[1][h][c] + to_b0[c], 0.f);
    __syncthreads();

    // layer1: 128 -> 64, 2-way k-split; rc = (r,c2)
    {
        int rc = tid & 127;
        int r  = rc >> 6;
        int c2 = rc & 63;
        float a = 0.f;
        int k0 = h*64;
        for (int k = k0; k < k0 + 64; ++k)
            a = fmaf(h1s[r][k], to_w1[k*64 + c2], a);
        p2[h][rc] = a;
    }
    __syncthreads();
    if (tid < 128) {
        int r  = tid >> 6;
        int c2 = tid & 63;
        float v = (p2[0][tid] + p2[1][tid] + to_b1[c2]) * amask[r0 + r];
        tau[(size_t)(r0 + r)*64 + c2] = v;
    }
}

extern "C" void kernel_launch(void* const* d_in, const int* in_sizes, int n_in,
                              void* d_out, int out_size, void* d_ws, size_t ws_size,
                              hipStream_t stream)
{
    const float* astate    = (const float*)d_in[0];
    const float* amask     = (const float*)d_in[1];
    const float* polylines = (const float*)d_in[2];
    const float* poly_mask = (const float*)d_in[3];
    const int*   ptype     = (const int*)d_in[4];
    const int*   tlst      = (const int*)d_in[5];
    const int*   route     = (const int*)d_in[6];
    const float* ae_w0 = (const float*)d_in[7];
    const float* ae_b0 = (const float*)d_in[8];
    const float* ae_w1 = (const float*)d_in[9];
    const float* ae_b1 = (const float*)d_in[10];
    const float* ae_w2 = (const float*)d_in[11];
    const float* ae_b2 = (const float*)d_in[12];
    const float* mp_w0 = (const float*)d_in[13];
    const float* mp_b0 = (const float*)d_in[14];
    const float* mp_w1 = (const float*)d_in[15];
    const float* mp_b1 = (const float*)d_in[16];
    const float* type_emb  = (const float*)d_in[17];
    const float* tl_emb    = (const float*)d_in[18];
    const float* route_emb = (const float*)d_in[19];
    const float* mo_w0 = (const float*)d_in[20];
    const float* mo_b0 = (const float*)d_in[21];
    const float* mo_w1 = (const float*)d_in[22];
    const float* mo_b1 = (const float*)d_in[23];
    const float* mr_w0 = (const float*)d_in[24];
    const float* mr_b0 = (const float*)d_in[25];
    const float* mr_w1 = (const float*)d_in[26];
    const float* mr_b1 = (const float*)d_in[27];
    const float* nr_w0 = (const float*)d_in[28];
    const float* nr_b0 = (const float*)d_in[29];
    const float* nr_w1 = (const float*)d_in[30];
    const float* nr_b1 = (const float*)d_in[31];
    const float* to_w0 = (const float*)d_in[32];
    const float* to_b0 = (const float*)d_in[33];
    const float* to_w1 = (const float*)d_in[34];
    const float* to_b1 = (const float*)d_in[35];

    float* tau     = (float*)d_out;                     // NT*64
    float* map_ctx = (float*)d_out + (size_t)NT*64;     // NT*128
    float* nbr_ctx = map_ctx + (size_t)NT*HH;           // NT*128

    float* ws         = (float*)d_ws;
    float* a_emb      = ws;                              // NT*HH
    float* a_embT     = a_emb  + (size_t)NT*HH;          // NT*HH   [B][T][H][N]
    float* map_node   = a_embT + (size_t)NT*HH;          // B*M*HH
    float* map_nodeT  = map_node + (size_t)BB*MM*HH;     // B*HH*MM [B][H][M]
    float* map_center = map_nodeT + (size_t)BB*MM*HH;    // B*M*2

    k_map_enc<<<BB*MM, 512, 0, stream>>>(polylines, poly_mask, ptype, tlst, route,
        mp_w0, mp_b0, mp_w1, mp_b1, type_emb, tl_emb, route_emb,
        mo_w0, mo_b0, mo_w1, mo_b1, map_node, map_nodeT, map_center);

    k_agent_enc<<<NT/4, 256, 0, stream>>>(astate, amask,
        ae_w0, ae_b0, ae_w1, ae_b1, ae_w2, ae_b2, a_emb, a_embT);

    k_map_attn<<<NT, 384, 0, stream>>>(astate, a_emb, map_node, map_nodeT,
        map_center, poly_mask, mr_w0, mr_b0, mr_w1, mr_b1, map_ctx);

    k_nbr_attn<<<NT, 256, 0, stream>>>(astate, amask, a_emb, a_embT,
        nr_w0, nr_b0, nr_w1, nr_b1, nbr_ctx);

    k_tau<<<NT/2, 256, 0, stream>>>(amask, a_emb, map_ctx, nbr_ctx,
        to_w0, to_b0, to_w1, to_b1, tau);
}

// Round 3
// 202.672 us; speedup vs baseline: 1.2764x; 1.1741x over previous
//
#include <hip/hip_runtime.h>
#include <math.h>

#define HH 128
#define BB 2
#define NN 48
#define TT 24
#define MM 192
#define LL 20
#define NT (BB*NN*TT)   /* 2304 */
#define RSQRT_H 0.08838834764831845f  /* 1/sqrt(128) */
#define RADIUS_C 30.0f

// ---------------- Kernel 1: map polyline encoder ----------------
// grid = B*M blocks, 512 threads: (pp = tid/128 in 0..3, c = tid%128)
__global__ __launch_bounds__(512) void k_map_enc(
    const float* __restrict__ polylines, const float* __restrict__ poly_mask,
    const int* __restrict__ ptype, const int* __restrict__ tlst, const int* __restrict__ route,
    const float* __restrict__ mp_w0, const float* __restrict__ mp_b0,
    const float* __restrict__ mp_w1, const float* __restrict__ mp_b1,
    const float* __restrict__ type_emb, const float* __restrict__ tl_emb,
    const float* __restrict__ route_emb,
    const float* __restrict__ mo_w0, const float* __restrict__ mo_b0,
    const float* __restrict__ mo_w1, const float* __restrict__ mo_b1,
    float* __restrict__ map_node, float* __restrict__ map_nodeT,
    float* __restrict__ map_center)
{
    int bm  = blockIdx.x;
    int tid = threadIdx.x;
    int pp  = tid >> 7;     // 0..3
    int c   = tid & 127;

    __shared__ float pts[LL*2];
    __shared__ float h1[LL][HH];
    __shared__ float mx[4][HH];
    __shared__ float hb[HH];
    __shared__ float pr[4][HH];
    __shared__ float hb2[HH];

    if (tid < LL*2) pts[tid] = polylines[(size_t)bm*LL*2 + tid];
    __syncthreads();

    {
        float w0x = mp_w0[c], w0y = mp_w0[HH + c], b0 = mp_b0[c];
        #pragma unroll
        for (int i = 0; i < 5; ++i) {
            int p = pp + 4*i;
            h1[p][c] = fmaxf(fmaf(pts[2*p], w0x, fmaf(pts[2*p+1], w0y, b0)), 0.f);
        }
    }
    if (tid < 2) {
        float s = 0.f;
        for (int p = 0; p < LL; ++p) s += pts[2*p + tid];
        map_center[bm*2 + tid] = s * (1.0f / LL);
    }
    __syncthreads();

    {
        float acc[5];
        float b1 = mp_b1[c];
        #pragma unroll
        for (int i = 0; i < 5; ++i) acc[i] = b1;
        for (int k = 0; k < HH; ++k) {
            float wv = mp_w1[k*HH + c];
            #pragma unroll
            for (int i = 0; i < 5; ++i) acc[i] = fmaf(h1[pp + 4*i][k], wv, acc[i]);
        }
        float m5 = acc[0];
        #pragma unroll
        for (int i = 1; i < 5; ++i) m5 = fmaxf(m5, acc[i]);
        mx[pp][c] = m5;
    }
    __syncthreads();

    if (tid < HH) {
        float hm = fmaxf(fmaxf(mx[0][c], mx[1][c]), fmaxf(mx[2][c], mx[3][c]));
        hm = fmaxf(hm, 0.f);
        int pt = ptype[bm]; pt = pt < 0 ? 0 : (pt > 3 ? 3 : pt);
        int tv = tlst[bm];  tv = tv < 0 ? 0 : (tv > 7 ? 7 : tv);
        int rv = route[bm]; rv = rv < 0 ? 0 : (rv > 1 ? 1 : rv);
        hm += type_emb[pt*HH + c] + tl_emb[tv*HH + c] + route_emb[rv*HH + c];
        hb[c] = hm;
    }
    __syncthreads();

    {
        float s = 0.f;
        int k0 = pp*32;
        for (int k = k0; k < k0 + 32; ++k) s = fmaf(hb[k], mo_w0[k*HH + c], s);
        pr[pp][c] = s;
    }
    __syncthreads();
    if (tid < HH) hb2[c] = fmaxf(pr[0][c] + pr[1][c] + pr[2][c] + pr[3][c] + mo_b0[c], 0.f);
    __syncthreads();
    {
        float s = 0.f;
        int k0 = pp*32;
        for (int k = k0; k < k0 + 32; ++k) s = fmaf(hb2[k], mo_w1[k*HH + c], s);
        pr[pp][c] = s;
    }
    __syncthreads();
    if (tid < HH) {
        float a3 = pr[0][c] + pr[1][c] + pr[2][c] + pr[3][c] + mo_b1[0*HH + c];
        float mk = (poly_mask[bm] > 0.5f) ? 1.f : 0.f;
        float v = a3 * mk;
        map_node[(size_t)bm*HH + c] = v;
        int b = bm / MM, m = bm % MM;
        map_nodeT[((size_t)b*HH + c)*MM + m] = v;
    }
}

// ---------------- Kernel 2: agent encoder ----------------
// grid = NT/4 blocks, 256 threads
__global__ __launch_bounds__(256) void k_agent_enc(
    const float* __restrict__ astate, const float* __restrict__ amask,
    const float* __restrict__ ae_w0, const float* __restrict__ ae_b0,
    const float* __restrict__ ae_w1, const float* __restrict__ ae_b1,
    const float* __restrict__ ae_w2, const float* __restrict__ ae_b2,
    float* __restrict__ a_emb)
{
    int r0  = blockIdx.x * 4;
    int tid = threadIdx.x;
    int h   = tid >> 7;
    int c   = tid & 127;

    __shared__ float xin[4][5];
    __shared__ float h1[4][HH];
    __shared__ float h2[4][HH];
    __shared__ float p1[2][4][HH];

    if (tid < 20) xin[tid/5][tid%5] = astate[(size_t)r0*5 + tid];
    __syncthreads();

    if (h == 0) {
        float b = ae_b0[c];
        float w[5];
        #pragma unroll
        for (int i = 0; i < 5; ++i) w[i] = ae_w0[i*HH + c];
        #pragma unroll
        for (int r = 0; r < 4; ++r) {
            float v = b;
            #pragma unroll
            for (int i = 0; i < 5; ++i) v = fmaf(xin[r][i], w[i], v);
            h1[r][c] = fmaxf(v, 0.f);
        }
    }
    __syncthreads();

    {
        float acc[4] = {0.f, 0.f, 0.f, 0.f};
        int k0 = h*64;
        for (int k = k0; k < k0 + 64; ++k) {
            float wv = ae_w1[k*HH + c];
            #pragma unroll
            for (int r = 0; r < 4; ++r) acc[r] = fmaf(h1[r][k], wv, acc[r]);
        }
        #pragma unroll
        for (int r = 0; r < 4; ++r) p1[h][r][c] = acc[r];
    }
    __syncthreads();
    {
        #pragma unroll
        for (int rr = 0; rr < 2; ++rr) {
            int r = h*2 + rr;
            h2[r][c] = fmaxf(p1[0][r][c] + p1[1][r][c] + ae_b1[c], 0.f);
        }
    }
    __syncthreads();

    {
        float acc[4] = {0.f, 0.f, 0.f, 0.f};
        int k0 = h*64;
        for (int k = k0; k < k0 + 64; ++k) {
            float wv = ae_w2[k*HH + c];
            #pragma unroll
            for (int r = 0; r < 4; ++r) acc[r] = fmaf(h2[r][k], wv, acc[r]);
        }
        #pragma unroll
        for (int r = 0; r < 4; ++r) p1[h][r][c] = acc[r];
    }
    __syncthreads();
    {
        #pragma unroll
        for (int rr = 0; rr < 2; ++rr) {
            int r = h*2 + rr;
            int row = r0 + r;
            float v = (p1[0][r][c] + p1[1][r][c] + ae_b2[c]) * amask[row];
            a_emb[(size_t)row*HH + c] = v;
        }
    }
}

// ---------------- Kernel 3: map cross-attention ----------------
// grid = NT/4 = 576 blocks, 256 threads; 4 rows (same b,n; t0..t0+3) per block
__global__ __launch_bounds__(256) void k_map_attn(
    const float* __restrict__ astate,
    const float* __restrict__ a_emb, const float* __restrict__ map_node,
    const float* __restrict__ map_nodeT, const float* __restrict__ map_center,
    const float* __restrict__ poly_mask,
    const float* __restrict__ mr_w0, const float* __restrict__ mr_b0,
    const float* __restrict__ mr_w1, const float* __restrict__ mr_b1,
    float* __restrict__ map_ctx)
{
    int bnt0 = blockIdx.x * 4;
    int b    = bnt0 / (NN*TT);
    int tid  = threadIdx.x;

    __shared__ float  mnL[16][MM];      // 12KB  chunk of map_nodeT
    __shared__ float4 w4L[HH];          // {w0x,w0y,w0z,b0}
    __shared__ float  w1L[HH];
    __shared__ float4 aq4L[HH];         // query per k, 4 rows
    __shared__ float  lg[4][MM];
    __shared__ float4 p4L[MM];
    __shared__ float  invL[4];
    __shared__ float  pc[2][4][HH];

    if (tid < HH) {
        int k = tid;
        w4L[k] = make_float4(mr_w0[k], mr_w0[HH+k], mr_w0[2*HH+k], mr_b0[k]);
        w1L[k] = mr_w1[k];
    }
    for (int idx = tid; idx < 4*HH; idx += 256) {
        int r = idx >> 7, k = idx & 127;
        ((float*)&aq4L[k])[r] = a_emb[(size_t)(bnt0 + r)*HH + k];
    }

    float rx[4], ry[4], rd[4];
    if (tid < MM) {
        float mcx = map_center[(b*MM + tid)*2];
        float mcy = map_center[(b*MM + tid)*2 + 1];
        #pragma unroll
        for (int r = 0; r < 4; ++r) {
            float px = astate[(size_t)(bnt0 + r)*5];
            float py = astate[(size_t)(bnt0 + r)*5 + 1];
            rx[r] = mcx - px; ry[r] = mcy - py;
            rd[r] = sqrtf(rx[r]*rx[r] + ry[r]*ry[r]);
        }
    }

    // chunk-staged phase A with load/compute overlap (single buffer, T14 pattern)
    const float* mnT = map_nodeT + (size_t)b*HH*MM;
    float4 st[3];
    #pragma unroll
    for (int i = 0; i < 3; ++i) {
        int q = tid + 256*i;               // < 768
        int kk = q / 48, mq = q % 48;
        st[i] = *(const float4*)(mnT + (size_t)kk*MM + mq*4);
    }
    float s[4]  = {0.f,0.f,0.f,0.f};
    float dt[4] = {0.f,0.f,0.f,0.f};
    for (int ch = 0; ch < 8; ++ch) {
        __syncthreads();                    // previous chunk's compute done
        #pragma unroll
        for (int i = 0; i < 3; ++i) {
            int q = tid + 256*i;
            int kk = q / 48, mq = q % 48;
            *(float4*)&mnL[kk][mq*4] = st[i];
        }
        __syncthreads();
        if (ch < 7) {
            #pragma unroll
            for (int i = 0; i < 3; ++i) {
                int q = tid + 256*i;
                int kk = q / 48, mq = q % 48;
                st[i] = *(const float4*)(mnT + (size_t)(ch+1)*16*MM + (size_t)kk*MM + mq*4);
            }
        }
        if (tid < MM) {
            int k0 = ch*16;
            #pragma unroll
            for (int kk = 0; kk < 16; ++kk) {
                int k = k0 + kk;
                float4 w  = w4L[k];
                float  w1 = w1L[k];
                float4 aq = aq4L[k];
                float  mn = mnL[kk][tid];
                #pragma unroll
                for (int r = 0; r < 4; ++r) {
                    float hv = fmaf(rx[r], w.x, fmaf(ry[r], w.y, fmaf(rd[r], w.z, w.w)));
                    s[r] = fmaf(fmaxf(hv, 0.f), w1, s[r]);
                }
                dt[0] = fmaf(aq.x, mn, dt[0]);
                dt[1] = fmaf(aq.y, mn, dt[1]);
                dt[2] = fmaf(aq.z, mn, dt[2]);
                dt[3] = fmaf(aq.w, mn, dt[3]);
            }
        }
    }

    if (tid < MM) {
        float pm = poly_mask[b*MM + tid];
        float b1 = mr_b1[0];
        #pragma unroll
        for (int r = 0; r < 4; ++r) {
            float lgt = fmaf(dt[r], RSQRT_H, s[r] + b1);
            lg[r][tid] = (pm > 0.5f) ? lgt : -1e9f;
        }
    }
    __syncthreads();

    // softmax: wave r handles row r
    {
        int r = tid >> 6, l = tid & 63;
        float v = fmaxf(fmaxf(lg[r][l], lg[r][l+64]), lg[r][l+128]);
        #pragma unroll
        for (int o = 32; o > 0; o >>= 1) v = fmaxf(v, __shfl_xor(v, o));
        float e0 = expf(lg[r][l] - v);
        float e1 = expf(lg[r][l+64] - v);
        float e2 = expf(lg[r][l+128] - v);
        lg[r][l] = e0; lg[r][l+64] = e1; lg[r][l+128] = e2;
        float sm = e0 + e1 + e2;
        #pragma unroll
        for (int o = 32; o > 0; o >>= 1) sm += __shfl_xor(sm, o);
        if (l == 0) invL[r] = 1.0f / sm;
    }
    __syncthreads();
    if (tid < MM) {
        p4L[tid] = make_float4(lg[0][tid]*invL[0], lg[1][tid]*invL[1],
                               lg[2][tid]*invL[2], lg[3][tid]*invL[3]);
    }
    __syncthreads();

    // phase C: each global mn load feeds 4 rows
    {
        int half = tid >> 7, c = tid & 127;
        float a0=0.f, a1=0.f, a2=0.f, a3=0.f;
        const float* mnb = map_node + ((size_t)b*MM + half*96)*HH + c;
        for (int m = 0; m < 96; ++m) {
            float mv = mnb[(size_t)m*HH];
            float4 p = p4L[half*96 + m];
            a0 = fmaf(p.x, mv, a0); a1 = fmaf(p.y, mv, a1);
            a2 = fmaf(p.z, mv, a2); a3 = fmaf(p.w, mv, a3);
        }
        pc[half][0][c]=a0; pc[half][1][c]=a1; pc[half][2][c]=a2; pc[half][3][c]=a3;
    }
    __syncthreads();
    for (int idx = tid; idx < 4*HH; idx += 256) {
        int r = idx >> 7, c = idx & 127;
        map_ctx[(size_t)(bnt0 + r)*HH + c] = pc[0][r][c] + pc[1][r][c];
    }
}

// ---------------- Kernel 4: neighbor attention ----------------
// grid = B*T*8 = 384 blocks, 256 threads; 6 n-rows per block share (b,t)
__global__ __launch_bounds__(256) void k_nbr_attn(
    const float* __restrict__ astate, const float* __restrict__ amask,
    const float* __restrict__ a_emb,
    const float* __restrict__ nr_w0, const float* __restrict__ nr_b0,
    const float* __restrict__ nr_w1, const float* __restrict__ nr_b1,
    float* __restrict__ nbr_ctx)
{
    int bid = blockIdx.x;
    int b   = bid / (TT*8);
    int rem = bid % (TT*8);
    int t   = rem / 8;
    int n0  = (rem % 8) * 6;
    int tid = threadIdx.x;

    __shared__ float  aVL[NN][129];     // a_emb tile, padded
    __shared__ float  pjL[NN][8];       // {px,py,vx,vy,mask}
    __shared__ float4 wAL[HH], wBL[HH];
    __shared__ float  aqL[HH][8];       // queries, 6 rows
    __shared__ float  sPL[4][6][NN], dPL[4][6][NN];
    __shared__ float  lgL[6][NN];
    __shared__ float  pL[NN][8];
    __shared__ float  pcL[2][6][HH];

    if (tid < NN) {
        int rj = (b*NN + tid)*TT + t;
        pjL[tid][0] = astate[(size_t)rj*5];
        pjL[tid][1] = astate[(size_t)rj*5 + 1];
        pjL[tid][2] = astate[(size_t)rj*5 + 3];
        pjL[tid][3] = astate[(size_t)rj*5 + 4];
        pjL[tid][4] = amask[rj];
    }
    if (tid < HH) {
        int k = tid;
        wAL[k] = make_float4(nr_w0[k], nr_w0[HH+k], nr_w0[2*HH+k], nr_w0[3*HH+k]);
        wBL[k] = make_float4(nr_w0[4*HH+k], nr_b0[k], nr_w1[k], 0.f);
    }
    #pragma unroll
    for (int i = 0; i < 6; ++i) {
        int q = tid + 256*i;            // < 1536
        int j = q >> 5, cq = q & 31;
        float4 v = *(const float4*)(a_emb + ((size_t)(b*NN + j)*TT + t)*HH + cq*4);
        aVL[j][cq*4+0] = v.x; aVL[j][cq*4+1] = v.y;
        aVL[j][cq*4+2] = v.z; aVL[j][cq*4+3] = v.w;
    }
    __syncthreads();
    for (int idx = tid; idx < 6*HH; idx += 256) {
        int r = idx >> 7, k = idx & 127;
        aqL[k][r] = aVL[n0 + r][k];
    }
    __syncthreads();

    int j  = tid % 48;
    int kg = tid / 48;                  // <4 active
    float s[6]  = {0,0,0,0,0,0};
    float dt[6] = {0,0,0,0,0,0};
    if (kg < 4) {
        float jx = pjL[j][0], jy = pjL[j][1], jvx = pjL[j][2], jvy = pjL[j][3];
        float dx[6], dy[6], dvx[6], dvy[6], dd[6];
        #pragma unroll
        for (int r = 0; r < 6; ++r) {
            dx[r]  = pjL[n0+r][0] - jx;  dy[r]  = pjL[n0+r][1] - jy;
            dvx[r] = pjL[n0+r][2] - jvx; dvy[r] = pjL[n0+r][3] - jvy;
            dd[r]  = sqrtf(dx[r]*dx[r] + dy[r]*dy[r]);
        }
        int k0 = kg*32;
        for (int kk = 0; kk < 32; ++kk) {
            int k = k0 + kk;
            float4 wa = wAL[k], wb = wBL[k];
            float4 aA = *(const float4*)&aqL[k][0];
            float4 aB = *(const float4*)&aqL[k][4];
            float  av = aVL[j][k];
            #pragma unroll
            for (int r = 0; r < 6; ++r) {
                float hv = fmaf(dx[r], wa.x, fmaf(dy[r], wa.y,
                           fmaf(dvx[r], wa.z, fmaf(dvy[r], wa.w,
                           fmaf(dd[r], wb.x, wb.y)))));
                s[r] = fmaf(fmaxf(hv, 0.f), wb.z, s[r]);
            }
            dt[0] = fmaf(aA.x, av, dt[0]); dt[1] = fmaf(aA.y, av, dt[1]);
            dt[2] = fmaf(aA.z, av, dt[2]); dt[3] = fmaf(aA.w, av, dt[3]);
            dt[4] = fmaf(aB.x, av, dt[4]); dt[5] = fmaf(aB.y, av, dt[5]);
        }
        #pragma unroll
        for (int r = 0; r < 6; ++r) { sPL[kg][r][j] = s[r]; dPL[kg][r][j] = dt[r]; }
    }
    __syncthreads();

    float b1 = nr_b1[0];
    for (int idx = tid; idx < 6*NN; idx += 256) {
        int r = idx / NN, jj = idx % NN;
        int ni = n0 + r;
        float ss = sPL[0][r][jj] + sPL[1][r][jj] + sPL[2][r][jj] + sPL[3][r][jj] + b1;
        float do2 = dPL[0][r][jj] + dPL[1][r][jj] + dPL[2][r][jj] + dPL[3][r][jj];
        float ddx = pjL[ni][0] - pjL[jj][0];
        float ddy = pjL[ni][1] - pjL[jj][1];
        float dist = sqrtf(ddx*ddx + ddy*ddy);
        bool ok = (pjL[ni][4] > 0.5f) && (pjL[jj][4] > 0.5f) &&
                  (dist <= RADIUS_C) && (jj != ni);
        lgL[r][jj] = ok ? fmaf(do2, RSQRT_H, ss) : -1e9f;
    }
    __syncthreads();

    {
        int wv = tid >> 6, l = tid & 63;
        for (int r = wv; r < 6; r += 4) {
            float v = (l < NN) ? lgL[r][l] : -3.4e38f;
            #pragma unroll
            for (int o = 32; o > 0; o >>= 1) v = fmaxf(v, __shfl_xor(v, o));
            float e = (l < NN) ? expf(lgL[r][l] - v) : 0.f;
            float sm = e;
            #pragma unroll
            for (int o = 32; o > 0; o >>= 1) sm += __shfl_xor(sm, o);
            if (l < NN) lgL[r][l] = e / sm;
        }
    }
    __syncthreads();
    if (tid < NN) {
        #pragma unroll
        for (int r = 0; r < 6; ++r) pL[tid][r] = lgL[r][tid];
        pL[tid][6] = 0.f; pL[tid][7] = 0.f;
    }
    __syncthreads();

    {
        int half = tid >> 7, c = tid & 127;
        float acc[6] = {0,0,0,0,0,0};
        for (int jj = half*24; jj < half*24 + 24; ++jj) {
            float av = aVL[jj][c];
            float4 pA = *(const float4*)&pL[jj][0];
            float4 pB = *(const float4*)&pL[jj][4];
            acc[0] = fmaf(pA.x, av, acc[0]); acc[1] = fmaf(pA.y, av, acc[1]);
            acc[2] = fmaf(pA.z, av, acc[2]); acc[3] = fmaf(pA.w, av, acc[3]);
            acc[4] = fmaf(pB.x, av, acc[4]); acc[5] = fmaf(pB.y, av, acc[5]);
        }
        #pragma unroll
        for (int r = 0; r < 6; ++r) pcL[half][r][c] = acc[r];
    }
    __syncthreads();
    for (int idx = tid; idx < 6*HH; idx += 256) {
        int r = idx >> 7, c = idx & 127;
        int row = (b*NN + n0 + r)*TT + t;
        nbr_ctx[(size_t)row*HH + c] = pcL[0][r][c] + pcL[1][r][c];
    }
}

// ---------------- Kernel 5: output MLP ----------------
// grid = NT/8 = 288 blocks, 512 threads; 8 rows per block
__global__ __launch_bounds__(512) void k_tau(
    const float* __restrict__ amask,
    const float* __restrict__ a_emb, const float* __restrict__ map_ctx,
    const float* __restrict__ nbr_ctx,
    const float* __restrict__ to_w0, const float* __restrict__ to_b0,
    const float* __restrict__ to_w1, const float* __restrict__ to_b1,
    float* __restrict__ tau)
{
    int r0  = blockIdx.x * 8;
    int tid = threadIdx.x;
    __shared__ float xinT[3*HH][8];
    __shared__ float p1L[4][8][HH];
    __shared__ float h1T[HH][8];
    __shared__ float p2L[8][8][64];

    #pragma unroll
    for (int i = 0; i < 2; ++i) {
        int q = tid + 512*i;
        if (q < 768) {
            int r = q / 96, kq = q % 96;
            const float* src;
            int co;
            if (kq < 32)      { src = a_emb;   co = kq; }
            else if (kq < 64) { src = map_ctx; co = kq - 32; }
            else              { src = nbr_ctx; co = kq - 64; }
            float4 v = *(const float4*)(src + (size_t)(r0 + r)*HH + co*4);
            int kbase = (kq < 32 ? 0 : (kq < 64 ? HH : 2*HH)) + co*4;
            xinT[kbase+0][r] = v.x; xinT[kbase+1][r] = v.y;
            xinT[kbase+2][r] = v.z; xinT[kbase+3][r] = v.w;
        }
    }
    __syncthreads();
    {
        int c = tid & 127, h = tid >> 7;   // h<4
        float acc[8] = {0,0,0,0,0,0,0,0};
        for (int k = h*96; k < h*96 + 96; ++k) {
            float wv = to_w0[k*HH + c];
            float4 xa = *(const float4*)&xinT[k][0];
            float4 xb = *(const float4*)&xinT[k][4];
            acc[0]=fmaf(xa.x,wv,acc[0]); acc[1]=fmaf(xa.y,wv,acc[1]);
            acc[2]=fmaf(xa.z,wv,acc[2]); acc[3]=fmaf(xa.w,wv,acc[3]);
            acc[4]=fmaf(xb.x,wv,acc[4]); acc[5]=fmaf(xb.y,wv,acc[5]);
            acc[6]=fmaf(xb.z,wv,acc[6]); acc[7]=fmaf(xb.w,wv,acc[7]);
        }
        #pragma unroll
        for (int r = 0; r < 8; ++r) p1L[h][r][c] = acc[r];
    }
    __syncthreads();
    for (int idx = tid; idx < 8*HH; idx += 512) {
        int r = idx >> 7, k = idx & 127;
        float v = p1L[0][r][k] + p1L[1][r][k] + p1L[2][r][k] + p1L[3][r][k] + to_b0[k];
        h1T[k][r] = fmaxf(v, 0.f);
    }
    __syncthreads();
    {
        int c2 = tid & 63, h2 = tid >> 6;  // h2<8
        float acc[8] = {0,0,0,0,0,0,0,0};
        for (int k = h2*16; k < h2*16 + 16; ++k) {
            float wv = to_w1[k*64 + c2];
            float4 xa = *(const float4*)&h1T[k][0];
            float4 xb = *(const float4*)&h1T[k][4];
            acc[0]=fmaf(xa.x,wv,acc[0]); acc[1]=fmaf(xa.y,wv,acc[1]);
            acc[2]=fmaf(xa.z,wv,acc[2]); acc[3]=fmaf(xa.w,wv,acc[3]);
            acc[4]=fmaf(xb.x,wv,acc[4]); acc[5]=fmaf(xb.y,wv,acc[5]);
            acc[6]=fmaf(xb.z,wv,acc[6]); acc[7]=fmaf(xb.w,wv,acc[7]);
        }
        #pragma unroll
        for (int r = 0; r < 8; ++r) p2L[h2][r][c2] = acc[r];
    }
    __syncthreads();
    {
        int r = tid >> 6, c2 = tid & 63;
        float v = 0.f;
        #pragma unroll
        for (int h2 = 0; h2 < 8; ++h2) v += p2L[h2][r][c2];
        v = (v + to_b1[c2]) * amask[r0 + r];
        tau[(size_t)(r0 + r)*64 + c2] = v;
    }
}

extern "C" void kernel_launch(void* const* d_in, const int* in_sizes, int n_in,
                              void* d_out, int out_size, void* d_ws, size_t ws_size,
                              hipStream_t stream)
{
    const float* astate    = (const float*)d_in[0];
    const float* amask     = (const float*)d_in[1];
    const float* polylines = (const float*)d_in[2];
    const float* poly_mask = (const float*)d_in[3];
    const int*   ptype     = (const int*)d_in[4];
    const int*   tlst      = (const int*)d_in[5];
    const int*   route     = (const int*)d_in[6];
    const float* ae_w0 = (const float*)d_in[7];
    const float* ae_b0 = (const float*)d_in[8];
    const float* ae_w1 = (const float*)d_in[9];
    const float* ae_b1 = (const float*)d_in[10];
    const float* ae_w2 = (const float*)d_in[11];
    const float* ae_b2 = (const float*)d_in[12];
    const float* mp_w0 = (const float*)d_in[13];
    const float* mp_b0 = (const float*)d_in[14];
    const float* mp_w1 = (const float*)d_in[15];
    const float* mp_b1 = (const float*)d_in[16];
    const float* type_emb  = (const float*)d_in[17];
    const float* tl_emb    = (const float*)d_in[18];
    const float* route_emb = (const float*)d_in[19];
    const float* mo_w0 = (const float*)d_in[20];
    const float* mo_b0 = (const float*)d_in[21];
    const float* mo_w1 = (const float*)d_in[22];
    const float* mo_b1 = (const float*)d_in[23];
    const float* mr_w0 = (const float*)d_in[24];
    const float* mr_b0 = (const float*)d_in[25];
    const float* mr_w1 = (const float*)d_in[26];
    const float* mr_b1 = (const float*)d_in[27];
    const float* nr_w0 = (const float*)d_in[28];
    const float* nr_b0 = (const float*)d_in[29];
    const float* nr_w1 = (const float*)d_in[30];
    const float* nr_b1 = (const float*)d_in[31];
    const float* to_w0 = (const float*)d_in[32];
    const float* to_b0 = (const float*)d_in[33];
    const float* to_w1 = (const float*)d_in[34];
    const float* to_b1 = (const float*)d_in[35];

    float* tau     = (float*)d_out;                     // NT*64
    float* map_ctx = (float*)d_out + (size_t)NT*64;     // NT*128
    float* nbr_ctx = map_ctx + (size_t)NT*HH;           // NT*128

    float* ws         = (float*)d_ws;
    float* a_emb      = ws;                              // NT*HH
    float* map_node   = a_emb + (size_t)NT*HH;           // B*M*HH
    float* map_nodeT  = map_node + (size_t)BB*MM*HH;     // B*HH*MM
    float* map_center = map_nodeT + (size_t)BB*MM*HH;    // B*M*2

    k_map_enc<<<BB*MM, 512, 0, stream>>>(polylines, poly_mask, ptype, tlst, route,
        mp_w0, mp_b0, mp_w1, mp_b1, type_emb, tl_emb, route_emb,
        mo_w0, mo_b0, mo_w1, mo_b1, map_node, map_nodeT, map_center);

    k_agent_enc<<<NT/4, 256, 0, stream>>>(astate, amask,
        ae_w0, ae_b0, ae_w1, ae_b1, ae_w2, ae_b2, a_emb);

    k_map_attn<<<NT/4, 256, 0, stream>>>(astate, a_emb, map_node, map_nodeT,
        map_center, poly_mask, mr_w0, mr_b0, mr_w1, mr_b1, map_ctx);

    k_nbr_attn<<<BB*TT*8, 256, 0, stream>>>(astate, amask, a_emb,
        nr_w0, nr_b0, nr_w1, nr_b1, nbr_ctx);

    k_tau<<<NT/8, 512, 0, stream>>>(amask, a_emb, map_ctx, nbr_ctx,
        to_w0, to_b0, to_w1, to_b1, tau);
}